// Round 14
// baseline (316.865 us; speedup 1.0000x reference)
//
#include <hip/hip_runtime.h>

// ChunkedSelfAttention: B=2, T=4096, H=16, Dh=Dv=128, CHUNK=2048, causal per chunk,
// RoPE(base 10000) on q,k. No 1/sqrt(d) scale. fp32 in/out, fp16 MFMA inside.
// R14 = R13 with single-buffered K/V: LDS 80KB -> 48KB -> 3 blocks/CU (24 waves/CU,
// 6 waves/SIMD, +50% resident parallelism). R12 proved staging isn't critical-path,
// so the double-buffer LDS was pure occupancy tax. __launch_bounds__(512,6) caps
// regs at 85 (current usage ~84). 16x16 MFMA swapped core, in-lane softmax,
// 4-bit-swizzled K tiles, per-wave swizzled P LDS.

#define T_TOT  4096
#define HH     16
#define DH     128
#define CHUNKL 2048
#define QT     128          // q rows per block (8 waves x 16)
#define KTILE  64           // keys per tile
#define NEGV   1e30f
#define L2E    1.44269504088896f
#define THRL2  11.5415603f  // defer-max threshold: 8 * log2(e)

typedef _Float16 f16;
typedef __attribute__((ext_vector_type(8)))  _Float16 f16x8;
typedef __attribute__((ext_vector_type(4)))  _Float16 f16x4;
typedef __attribute__((ext_vector_type(4)))  float    f32x4;

#define AS_G(p) ((const __attribute__((address_space(1))) void*)(p))
#define AS_L(p) ((__attribute__((address_space(3))) void*)(p))

__device__ __forceinline__ f32x4 mfma16(f16x8 a, f16x8 b, f32x4 c) {
    return __builtin_amdgcn_mfma_f32_16x16x32_f16(a, b, c, 0, 0, 0);
}

// cos at tab[t*64+d], sin at tab[T*64 + t*64+d], d in [0,64)
__global__ void rope_table_kernel(float* __restrict__ tab, const int* __restrict__ startp) {
    int gid = blockIdx.x * blockDim.x + threadIdx.x;   // [0, 4096*64)
    int t = gid >> 6, d = gid & 63;
    float pos  = (float)(t + *startp);
    float invf = expf((float)d * (-9.210340371976184f / 64.0f));
    float s, c;
    sincosf(pos * invf, &s, &c);
    tab[gid] = c;
    tab[T_TOT * 64 + gid] = s;
}

// Gather-based prep, 64-key tiles (8192 f16 = 16KB per tile).
// One thread per 16B OUTPUT chunk; writes fully coalesced.
//   Kws : element (key,d)  at tile*8192 + key*128 + (d ^ ((key&15)<<3))   [4-bit swz]
//   VTws: element (d,key)  at tile*8192 + d*64  + (key ^ ((d&7)<<3))
__global__ void prep_kv_kernel(const float* __restrict__ K, const float* __restrict__ V,
                               const float* __restrict__ tab,
                               f16* __restrict__ Kws, f16* __restrict__ VTws) {
    const int half = (2 * T_TOT * HH * DH) / 8;        // 2,097,152 chunks per part
    int gid = blockIdx.x * blockDim.x + threadIdx.x;
    if (gid < half) {
        // ---- K path ----
        const int tile = gid >> 10, idx = gid & 1023;
        const int key = idx >> 4, c8 = idx & 15;       // key [0,64), 16 chunks/key-row
        const int dsw0 = c8 << 3;
        const int d0   = dsw0 ^ ((key & 15) << 3);     // source d, 8-aligned
        const int kt = tile & 31, h = (tile >> 5) & 15, n = (tile >> 9) & 1, b = tile >> 10;
        const int t  = n * CHUNKL + kt * KTILE + key;
        const float* kp = K + ((size_t)(b * T_TOT + t) * HH + h) * DH;
        const int dl = d0 & 63;
        f32x4 xm0 = *(const f32x4*)(kp + d0);
        f32x4 xm1 = *(const f32x4*)(kp + d0 + 4);
        f32x4 xo0 = *(const f32x4*)(kp + (d0 ^ 64));
        f32x4 xo1 = *(const f32x4*)(kp + (d0 ^ 64) + 4);
        f32x4 cc0 = *(const f32x4*)(tab + t * 64 + dl);
        f32x4 cc1 = *(const f32x4*)(tab + t * 64 + dl + 4);
        f32x4 ss0 = *(const f32x4*)(tab + T_TOT * 64 + t * 64 + dl);
        f32x4 ss1 = *(const f32x4*)(tab + T_TOT * 64 + t * 64 + dl + 4);
        const float sgn = (d0 < 64) ? -1.f : 1.f;
        f16x8 out;
#pragma unroll
        for (int j = 0; j < 4; ++j) {
            out[j]     = (f16)(xm0[j] * cc0[j] + sgn * xo0[j] * ss0[j]);
            out[4 + j] = (f16)(xm1[j] * cc1[j] + sgn * xo1[j] * ss1[j]);
        }
        *(f16x8*)&Kws[(size_t)tile * 8192 + key * DH + dsw0] = out;
    } else {
        // ---- V path ----
        const int oc = gid - half;
        const int tile = oc >> 10, idx = oc & 1023;
        const int d = idx >> 3, c8 = idx & 7;          // d [0,128), 8 chunks/d-row
        const int ksw0 = c8 << 3;
        const int key0 = ksw0 ^ ((d & 7) << 3);        // 8-aligned, [0,64)
        const int kt = tile & 31, h = (tile >> 5) & 15, n = (tile >> 9) & 1, b = tile >> 10;
        const int t0 = n * CHUNKL + kt * KTILE + key0;
        const float* vp = V + ((size_t)(b * T_TOT + t0) * HH + h) * DH + d;
        f16x8 out;
#pragma unroll
        for (int j = 0; j < 8; ++j)
            out[j] = (f16)vp[(size_t)j * (HH * DH)];
        *(f16x8*)&VTws[(size_t)tile * 8192 + d * KTILE + ksw0] = out;
    }
}

// ---------------------------------------------------------------------------
// Fast attention: 512 threads = 8 waves, each wave 16 q-rows of one 128-row tile.
// Single-buffered K/V (48KB LDS -> 3 blocks/CU). 16x16 MFMA, swapped operands.
__global__ __launch_bounds__(512, 6)
void attn_fast_kernel(const float* __restrict__ Q, const f16* __restrict__ Kws,
                      const f16* __restrict__ VTws, const float* __restrict__ tab,
                      float* __restrict__ O)
{
    __shared__ f16 Kl[KTILE * DH];        // swizzled [key][d]   16 KB
    __shared__ f16 VTl[KTILE * DH];       // swizzled [d][key]   16 KB
    __shared__ f16 Pl[8][16 * 64];        // per-wave P [q][key], 16B-block XOR  16 KB

    // XCD-chunked: longest q-tiles first within each XCD chunk.
    const int bid = blockIdx.x;           // [0, 1024)
    const int sb  = (bid & 7) * 128 + (bid >> 3);
    const int qt  = 15 - (sb & 15);
    const int bnh = sb >> 4;
    const int hd = bnh & 15, n = (bnh >> 4) & 1, b = bnh >> 5;

    const int tid = threadIdx.x;
    const int w   = tid >> 6;             // 0..7
    const int l   = tid & 63;
    const int g   = l >> 4;               // 0..3
    const int m   = l & 15;               // q column / key row / d row

    const int q0 = qt * QT;
    const size_t bh = (size_t)b * T_TOT * (HH * DH) + (size_t)hd * DH;
    const size_t tile0 = (size_t)bnh * (32 * 8192);

    // ---------------- Q fragments: RoPE'd via table, x log2(e) ------------------
    const int qr = q0 + w * 16 + m;       // chunk-local q row of this lane
    const int tg = n * CHUNKL + qr;
    const float* qp = Q + bh + (size_t)tg * (HH * DH);

    f16x8 qf[4];                          // [kc]: Q[q][d = kc*32 + 8g + j]
#pragma unroll
    for (int kc = 0; kc < 4; ++kc) {
        const int dbase = kc * 32 + g * 8;
        const int dl    = dbase & 63;
        f32x4 xa0 = *(const f32x4*)(qp + dbase);
        f32x4 xa1 = *(const f32x4*)(qp + dbase + 4);
        f32x4 xb0 = *(const f32x4*)(qp + (dbase ^ 64));
        f32x4 xb1 = *(const f32x4*)(qp + (dbase ^ 64) + 4);
        float cc[8], ss[8];
        *(f32x4*)&cc[0] = *(const f32x4*)(tab + tg * 64 + dl);
        *(f32x4*)&cc[4] = *(const f32x4*)(tab + tg * 64 + dl + 4);
        *(f32x4*)&ss[0] = *(const f32x4*)(tab + T_TOT * 64 + tg * 64 + dl);
        *(f32x4*)&ss[4] = *(const f32x4*)(tab + T_TOT * 64 + tg * 64 + dl + 4);
        const float sgn = (dbase < 64) ? -1.f : 1.f;
        float xa[8] = {xa0[0],xa0[1],xa0[2],xa0[3],xa1[0],xa1[1],xa1[2],xa1[3]};
        float xb[8] = {xb0[0],xb0[1],xb0[2],xb0[3],xb1[0],xb1[1],xb1[2],xb1[3]};
        f16x8 f;
#pragma unroll
        for (int j = 0; j < 8; ++j)
            f[j] = (f16)((xa[j] * cc[j] + sgn * xb[j] * ss[j]) * L2E);
        qf[kc] = f;
    }

    // accumulators: o[dt] = O[d = dt*16 + 4g + r][q = m-row]
    f32x4 o[8];
    float mrun = -NEGV, lrun = 0.f;       // per-lane, q = m; g-lanes duplicate
    const f32x4 ZERO4 = {0.f, 0.f, 0.f, 0.f};
#pragma unroll
    for (int dt = 0; dt < 8; ++dt) o[dt] = ZERO4;

    // ---------------- main loop: single-buffer, 2 barriers/tile -----------------
    const int nkt = 2 * qt + 2;

    for (int kt = 0; kt < nkt; ++kt) {
        // stage tile kt (32KB block-wide; 4 x 16B per thread)
        {
            const f16* ks_ = Kws  + tile0 + (size_t)kt * 8192;
            const f16* vs_ = VTws + tile0 + (size_t)kt * 8192;
            __builtin_amdgcn_global_load_lds(AS_G(ks_ + tid * 8),        AS_L(&Kl[tid * 8]),         16, 0, 0);
            __builtin_amdgcn_global_load_lds(AS_G(ks_ + 4096 + tid * 8), AS_L(&Kl[4096 + tid * 8]),  16, 0, 0);
            __builtin_amdgcn_global_load_lds(AS_G(vs_ + tid * 8),        AS_L(&VTl[tid * 8]),        16, 0, 0);
            __builtin_amdgcn_global_load_lds(AS_G(vs_ + 4096 + tid * 8), AS_L(&VTl[4096 + tid * 8]), 16, 0, 0);
        }
        __syncthreads();                  // drains vmcnt: buf ready for all waves

        const bool active = (kt * KTILE) < (q0 + w * 16 + 16);
        if (active) {
            // ---- QK^T swapped: s[ts] = S[key = kt*64 + ts*16 + 4g + r][q = m] ----
            f32x4 s[4];
#pragma unroll
            for (int ts = 0; ts < 4; ++ts) s[ts] = ZERO4;

            __builtin_amdgcn_s_setprio(1);
#pragma unroll
            for (int kc = 0; kc < 4; ++kc) {
#pragma unroll
                for (int ts = 0; ts < 4; ++ts) {
                    const int key = ts * 16 + m;
                    f16x8 kf = *(const f16x8*)&Kl[key * DH + ((kc * 32 + 8 * g) ^ (m * 8))];
                    s[ts] = mfma16(kf, qf[kc], s[ts]);
                }
            }
            __builtin_amdgcn_s_setprio(0);

            // ---- mask (wave's diagonal tiles) ----
            if ((kt + 1) * KTILE > q0 + w * 16) {
#pragma unroll
                for (int ts = 0; ts < 4; ++ts)
#pragma unroll
                    for (int r = 0; r < 4; ++r) {
                        const int key = kt * KTILE + ts * 16 + 4 * g + r;
                        if (key > qr) s[ts][r] = -NEGV;
                    }
            }

            // ---- row max: in-lane max3 tree (16 vals) + 2 shuffles ----
            float ma = fmaxf(fmaxf(s[0][0], s[0][1]), fmaxf(s[0][2], s[0][3]));
            float mb = fmaxf(fmaxf(s[1][0], s[1][1]), fmaxf(s[1][2], s[1][3]));
            float mc = fmaxf(fmaxf(s[2][0], s[2][1]), fmaxf(s[2][2], s[2][3]));
            float md = fmaxf(fmaxf(s[3][0], s[3][1]), fmaxf(s[3][2], s[3][3]));
            float mx = fmaxf(fmaxf(ma, mb), fmaxf(mc, md));
            mx = fmaxf(mx, __shfl_xor(mx, 16));
            mx = fmaxf(mx, __shfl_xor(mx, 32));

            // ---- defer-max rescale (q = m -> al lane-local) ----
            if (__any(mx > mrun + THRL2)) {
                const float mn = fmaxf(mrun, mx);
                const float al = exp2f(mrun - mn);
                mrun = mn;
                lrun *= al;
#pragma unroll
                for (int dt = 0; dt < 8; ++dt)
#pragma unroll
                    for (int r = 0; r < 4; ++r) o[dt][r] *= al;
            }

            // ---- p = exp2(s - m); lane-local partial sum ----
#pragma unroll
            for (int ts = 0; ts < 4; ++ts)
#pragma unroll
                for (int r = 0; r < 4; ++r) s[ts][r] = exp2f(s[ts][r] - mrun);
            {
                float p0 = (s[0][0] + s[0][1]) + (s[0][2] + s[0][3]);
                float p1 = (s[1][0] + s[1][1]) + (s[1][2] + s[1][3]);
                float p2 = (s[2][0] + s[2][1]) + (s[2][2] + s[2][3]);
                float p3 = (s[3][0] + s[3][1]) + (s[3][2] + s[3][3]);
                lrun += (p0 + p1) + (p2 + p3);
            }

            // ---- P -> per-wave LDS, 16B-block XOR swizzle (8B stores) ----
#pragma unroll
            for (int ts = 0; ts < 4; ++ts) {
                f16x4 pk;
                pk[0] = (f16)s[ts][0];
                pk[1] = (f16)s[ts][1];
                pk[2] = (f16)s[ts][2];
                pk[3] = (f16)s[ts][3];
                const int blk = (2 * ts + (g >> 1)) ^ (m & 7);
                *(f16x4*)&Pl[w][m * 64 + blk * 8 + (g & 1) * 4] = pk;
            }

            // ---- PV swapped: o[dt] += V^T(A) x P(B) ----
            __builtin_amdgcn_s_setprio(1);
#pragma unroll
            for (int kc = 0; kc < 2; ++kc) {
                f16x8 pb = *(const f16x8*)&Pl[w][m * 64 + ((kc * 4 + g) ^ (m & 7)) * 8];
#pragma unroll
                for (int dt = 0; dt < 8; ++dt) {
                    const int d = dt * 16 + m;
                    f16x8 vf = *(const f16x8*)&VTl[d * KTILE + ((kc * 32 + 8 * g) ^ ((m & 7) * 8))];
                    o[dt] = mfma16(vf, pb, o[dt]);
                }
            }
            __builtin_amdgcn_s_setprio(0);
        }

        __syncthreads();                  // all waves done reading buf -> safe to restage
    }

    // ---------------- epilogue: merge l across g, normalize, store --------------
    float lt = lrun;
    lt += __shfl_xor(lt, 16);
    lt += __shfl_xor(lt, 32);
    const float inv = 1.0f / lt;
    float* op = O + bh + (size_t)tg * (HH * DH);
#pragma unroll
    for (int dt = 0; dt < 8; ++dt) {
        f32x4 val;
#pragma unroll
        for (int r = 0; r < 4; ++r) val[r] = o[dt][r] * inv;
        *(f32x4*)&op[dt * 16 + 4 * g] = val;     // d = dt*16 + 4g + r
    }
}

// ---------------------------------------------------------------------------
// Fallback (no/small ws): self-contained, RoPE inline. (R2-style, known good.)
__global__ __launch_bounds__(256, 2)
void attn_kernel(const float* __restrict__ Q, const float* __restrict__ K,
                 const float* __restrict__ V, const int* __restrict__ startp,
                 float* __restrict__ O)
{
    __shared__ f16 Kl[KTILE * DH];
    __shared__ f16 VTl[DH * KTILE];
    __shared__ f16 Pl[4][32 * 72];

    const int bid = blockIdx.x;
    const int qt  = 15 - (bid & 15);
    const int bnh = bid >> 4;
    const int h = bnh & 15, n = (bnh >> 4) & 1, b = bnh >> 5;

    const int tid  = threadIdx.x;
    const int w    = tid >> 6;
    const int lane = tid & 63;
    const int g    = lane >> 4, m = lane & 15;

    const int q0 = qt * QT;
    const size_t bh = (size_t)b * T_TOT * (HH * DH) + (size_t)h * DH;
    const int start = *startp;

    f16x8  qf[2][4];
    float  mrun[2][4], lrun[2][4];
    f32x4  o[2][8];
    const f32x4 ZERO4 = {0.f, 0.f, 0.f, 0.f};

#pragma unroll
    for (int rs = 0; rs < 2; ++rs) {
#pragma unroll
        for (int r = 0; r < 4; ++r) { mrun[rs][r] = -NEGV; lrun[rs][r] = 0.f; }
#pragma unroll
        for (int dt = 0; dt < 8; ++dt) o[rs][dt] = ZERO4;

        const int tg = n * CHUNKL + q0 + w * 32 + rs * 16 + m;
        const float* qp = Q + bh + (size_t)tg * (HH * DH);
#pragma unroll
        for (int kc = 0; kc < 4; ++kc) {
            const int dbase = kc * 32 + g * 8;
            const int dlo   = dbase & 63;
            f32x4 xa0 = *(const f32x4*)(qp + dbase);
            f32x4 xa1 = *(const f32x4*)(qp + dbase + 4);
            f32x4 xb0 = *(const f32x4*)(qp + (dbase ^ 64));
            f32x4 xb1 = *(const f32x4*)(qp + (dbase ^ 64) + 4);
            float cc[8], ss[8];
#pragma unroll
            for (int j = 0; j < 8; ++j) {
                float invf = expf((float)(dlo + j) * (-9.210340371976184f / 64.0f));
                sincosf((float)(tg + start) * invf, &ss[j], &cc[j]);
            }
            const float sgn = (dbase < 64) ? -1.f : 1.f;
            float xa[8] = {xa0[0],xa0[1],xa0[2],xa0[3],xa1[0],xa1[1],xa1[2],xa1[3]};
            float xb[8] = {xb0[0],xb0[1],xb0[2],xb0[3],xb1[0],xb1[1],xb1[2],xb1[3]};
            f16x8 f;
#pragma unroll
            for (int j = 0; j < 8; ++j) f[j] = (f16)(xa[j] * cc[j] + sgn * xb[j] * ss[j]);
            qf[rs][kc] = f;
        }
    }

    const int nkt = 2 * qt + 2;
    for (int kt = 0; kt < nkt; ++kt) {
        __syncthreads();
#pragma unroll
        for (int it = 0; it < 4; ++it) {
            const int tau = tid + 256 * it;
            const int row = tau >> 4;
            const int d0  = (tau & 15) << 2;
            const int tg  = n * CHUNKL + kt * KTILE + row;
            const float* kp = K + bh + (size_t)tg * (HH * DH);
            f32x4 xa = *(const f32x4*)(kp + d0);
            f32x4 xb = *(const f32x4*)(kp + d0 + 64);
            f32x4 cc, ss;
#pragma unroll
            for (int j = 0; j < 4; ++j) {
                float invf = expf((float)(d0 + j) * (-9.210340371976184f / 64.0f));
                float sv, cv;
                sincosf((float)(tg + start) * invf, &sv, &cv);
                cc[j] = cv; ss[j] = sv;
            }
            f16x4 oA, oB;
#pragma unroll
            for (int j = 0; j < 4; ++j) {
                oA[j] = (f16)(xa[j] * cc[j] - xb[j] * ss[j]);
                oB[j] = (f16)(xb[j] * cc[j] + xa[j] * ss[j]);
            }
            const int sw = (row & 7) << 3;
            *(f16x4*)&Kl[row * DH + (d0 ^ sw)]        = oA;
            *(f16x4*)&Kl[row * DH + ((d0 + 64) ^ sw)] = oB;
        }
#pragma unroll
        for (int it = 0; it < 8; ++it) {
            const int tau = tid + 256 * it;
            const int key = tau & 63;
            const int d0  = (tau >> 6) << 2;
            const int tg  = n * CHUNKL + kt * KTILE + key;
            f32x4 x = *(const f32x4*)(V + bh + (size_t)tg * (HH * DH) + d0);
#pragma unroll
            for (int j = 0; j < 4; ++j) {
                const int d = d0 + j;
                VTl[d * KTILE + (key ^ ((d & 7) << 3))] = (f16)x[j];
            }
        }
        __syncthreads();

        const bool active = (kt * KTILE) < (q0 + w * 32 + 32);
        if (active) {
            f32x4 sa[2][4];
#pragma unroll
            for (int rs = 0; rs < 2; ++rs)
#pragma unroll
                for (int nt = 0; nt < 4; ++nt) sa[rs][nt] = ZERO4;
#pragma unroll
            for (int nt = 0; nt < 4; ++nt) {
                const int key = nt * 16 + m;
                const int swk = (key & 7) << 3;
#pragma unroll
                for (int kc = 0; kc < 4; ++kc) {
                    f16x8 bf = *(const f16x8*)&Kl[key * DH + ((kc * 32 + g * 8) ^ swk)];
                    sa[0][nt] = mfma16(qf[0][kc], bf, sa[0][nt]);
                    sa[1][nt] = mfma16(qf[1][kc], bf, sa[1][nt]);
                }
            }
            const bool domask = (kt >= 2 * qt);
#pragma unroll
            for (int rs = 0; rs < 2; ++rs) {
                if (domask) {
#pragma unroll
                    for (int nt = 0; nt < 4; ++nt) {
                        const int key = kt * KTILE + nt * 16 + m;
#pragma unroll
                        for (int r = 0; r < 4; ++r) {
                            const int qr = q0 + w * 32 + rs * 16 + 4 * g + r;
                            if (key > qr) sa[rs][nt][r] = -NEGV;
                        }
                    }
                }
                float mx[4];
#pragma unroll
                for (int r = 0; r < 4; ++r)
                    mx[r] = fmaxf(fmaxf(sa[rs][0][r], sa[rs][1][r]),
                                  fmaxf(sa[rs][2][r], sa[rs][3][r]));
#pragma unroll
                for (int off = 1; off < 16; off <<= 1)
#pragma unroll
                    for (int r = 0; r < 4; ++r)
                        mx[r] = fmaxf(mx[r], __shfl_xor(mx[r], off));
                float al[4], ps[4];
#pragma unroll
                for (int r = 0; r < 4; ++r) {
                    const float mn = fmaxf(mrun[rs][r], mx[r]);
                    al[r] = exp2f((mrun[rs][r] - mn) * L2E);
                    mrun[rs][r] = mn;
                    ps[r] = 0.f;
                }
#pragma unroll
                for (int nt = 0; nt < 4; ++nt)
#pragma unroll
                    for (int r = 0; r < 4; ++r) {
                        const float p = exp2f((sa[rs][nt][r] - mrun[rs][r]) * L2E);
                        sa[rs][nt][r] = p;
                        ps[r] += p;
                    }
#pragma unroll
                for (int off = 1; off < 16; off <<= 1)
#pragma unroll
                    for (int r = 0; r < 4; ++r)
                        ps[r] += __shfl_xor(ps[r], off);
#pragma unroll
                for (int r = 0; r < 4; ++r)
                    lrun[rs][r] = lrun[rs][r] * al[r] + ps[r];
#pragma unroll
                for (int dt = 0; dt < 8; ++dt)
#pragma unroll
                    for (int r = 0; r < 4; ++r)
                        o[rs][dt][r] *= al[r];
#pragma unroll
                for (int nt = 0; nt < 4; ++nt)
#pragma unroll
                    for (int r = 0; r < 4; ++r)
                        Pl[w][(rs * 16 + 4 * g + r) * 72 + nt * 16 + m] = (f16)sa[rs][nt][r];
            }
            f16x8 pa[2][2];
#pragma unroll
            for (int rs = 0; rs < 2; ++rs)
#pragma unroll
                for (int kc = 0; kc < 2; ++kc)
                    pa[rs][kc] = *(const f16x8*)&Pl[w][(rs * 16 + m) * 72 + kc * 32 + g * 8];
#pragma unroll
            for (int dt = 0; dt < 8; ++dt) {
                const int d   = dt * 16 + m;
                const int swv = (d & 7) << 3;
#pragma unroll
                for (int kc = 0; kc < 2; ++kc) {
                    f16x8 vf = *(const f16x8*)&VTl[d * KTILE + ((kc * 32 + g * 8) ^ swv)];
                    o[0][dt] = mfma16(pa[0][kc], vf, o[0][dt]);
                    o[1][dt] = mfma16(pa[1][kc], vf, o[1][dt]);
                }
            }
        }
    }

#pragma unroll
    for (int rs = 0; rs < 2; ++rs) {
#pragma unroll
        for (int r = 0; r < 4; ++r) {
            const float inv = 1.0f / lrun[rs][r];
            const int tg = n * CHUNKL + q0 + w * 32 + rs * 16 + 4 * g + r;
            float* op = O + bh + (size_t)tg * (HH * DH);
#pragma unroll
            for (int dt = 0; dt < 8; ++dt)
                op[dt * 16 + m] = o[rs][dt][r] * inv;
        }
    }
}

extern "C" void kernel_launch(void* const* d_in, const int* in_sizes, int n_in,
                              void* d_out, int out_size, void* d_ws, size_t ws_size,
                              hipStream_t stream) {
    const float* q = (const float*)d_in[0];
    const float* k = (const float*)d_in[1];
    const float* v = (const float*)d_in[2];
    const int* start = (const int*)d_in[3];
    float* out = (float*)d_out;

    const size_t tab_elems = (size_t)2 * T_TOT * 64;               // 2MB
    const size_t kv_elems  = (size_t)2 * T_TOT * HH * DH;          // 32MB each (f16)
    const size_t need = tab_elems * sizeof(float) + 2 * kv_elems * sizeof(f16); // 66MB

    if (ws_size >= need) {
        float* tab = (float*)d_ws;
        f16* Kws  = (f16*)((char*)d_ws + tab_elems * sizeof(float));
        f16* VTws = Kws + kv_elems;
        rope_table_kernel<<<(T_TOT * 64) / 256, 256, 0, stream>>>(tab, start);
        prep_kv_kernel<<<(int)(2 * (kv_elems / 8) / 256), 256, 0, stream>>>(k, v, tab, Kws, VTws);
        attn_fast_kernel<<<1024, 512, 0, stream>>>(q, Kws, VTws, tab, out);
    } else {
        attn_kernel<<<64 * 16, 256, 0, stream>>>(q, k, v, start, out);
    }
}

// Round 15
// 200.292 us; speedup vs baseline: 1.5820x; 1.5820x over previous
//
#include <hip/hip_runtime.h>

// ChunkedSelfAttention: B=2, T=4096, H=16, Dh=Dv=128, CHUNK=2048, causal per chunk,
// RoPE(base 10000) on q,k. No 1/sqrt(d) scale. fp32 in/out, fp16 MFMA inside.
// R15 = R13 per-wave code with 256-thread blocks (4 waves, 64 q-rows):
// LDS 40KB -> 4 blocks/CU = 16 waves/CU at 4-wave granularity (better backfill than
// R13's 2x8-wave). launch_bounds(256,4) -> VGPR cap 128, ~88 used, no spills
// (R14's (512,6) cap=85 spilled catastrophically). 16x16 MFMA swapped core,
// in-lane softmax, defer-max, 4-bit-swizzled K tiles, per-wave swizzled P LDS.

#define T_TOT  4096
#define HH     16
#define DH     128
#define CHUNKL 2048
#define KTILE  64           // keys per tile
#define NEGV   1e30f
#define L2E    1.44269504088896f
#define THRL2  11.5415603f  // defer-max threshold: 8 * log2(e)

typedef _Float16 f16;
typedef __attribute__((ext_vector_type(8)))  _Float16 f16x8;
typedef __attribute__((ext_vector_type(4)))  _Float16 f16x4;
typedef __attribute__((ext_vector_type(4)))  float    f32x4;

#define AS_G(p) ((const __attribute__((address_space(1))) void*)(p))
#define AS_L(p) ((__attribute__((address_space(3))) void*)(p))

__device__ __forceinline__ f32x4 mfma16(f16x8 a, f16x8 b, f32x4 c) {
    return __builtin_amdgcn_mfma_f32_16x16x32_f16(a, b, c, 0, 0, 0);
}

// cos at tab[t*64+d], sin at tab[T*64 + t*64+d], d in [0,64)
__global__ void rope_table_kernel(float* __restrict__ tab, const int* __restrict__ startp) {
    int gid = blockIdx.x * blockDim.x + threadIdx.x;   // [0, 4096*64)
    int t = gid >> 6, d = gid & 63;
    float pos  = (float)(t + *startp);
    float invf = expf((float)d * (-9.210340371976184f / 64.0f));
    float s, c;
    sincosf(pos * invf, &s, &c);
    tab[gid] = c;
    tab[T_TOT * 64 + gid] = s;
}

// Gather-based prep, 64-key tiles (8192 f16 = 16KB per tile).
// One thread per 16B OUTPUT chunk; writes fully coalesced.
//   Kws : element (key,d)  at tile*8192 + key*128 + (d ^ ((key&15)<<3))   [4-bit swz]
//   VTws: element (d,key)  at tile*8192 + d*64  + (key ^ ((d&7)<<3))
__global__ void prep_kv_kernel(const float* __restrict__ K, const float* __restrict__ V,
                               const float* __restrict__ tab,
                               f16* __restrict__ Kws, f16* __restrict__ VTws) {
    const int half = (2 * T_TOT * HH * DH) / 8;        // 2,097,152 chunks per part
    int gid = blockIdx.x * blockDim.x + threadIdx.x;
    if (gid < half) {
        // ---- K path ----
        const int tile = gid >> 10, idx = gid & 1023;
        const int key = idx >> 4, c8 = idx & 15;       // key [0,64), 16 chunks/key-row
        const int dsw0 = c8 << 3;
        const int d0   = dsw0 ^ ((key & 15) << 3);     // source d, 8-aligned
        const int kt = tile & 31, h = (tile >> 5) & 15, n = (tile >> 9) & 1, b = tile >> 10;
        const int t  = n * CHUNKL + kt * KTILE + key;
        const float* kp = K + ((size_t)(b * T_TOT + t) * HH + h) * DH;
        const int dl = d0 & 63;
        f32x4 xm0 = *(const f32x4*)(kp + d0);
        f32x4 xm1 = *(const f32x4*)(kp + d0 + 4);
        f32x4 xo0 = *(const f32x4*)(kp + (d0 ^ 64));
        f32x4 xo1 = *(const f32x4*)(kp + (d0 ^ 64) + 4);
        f32x4 cc0 = *(const f32x4*)(tab + t * 64 + dl);
        f32x4 cc1 = *(const f32x4*)(tab + t * 64 + dl + 4);
        f32x4 ss0 = *(const f32x4*)(tab + T_TOT * 64 + t * 64 + dl);
        f32x4 ss1 = *(const f32x4*)(tab + T_TOT * 64 + t * 64 + dl + 4);
        const float sgn = (d0 < 64) ? -1.f : 1.f;
        f16x8 out;
#pragma unroll
        for (int j = 0; j < 4; ++j) {
            out[j]     = (f16)(xm0[j] * cc0[j] + sgn * xo0[j] * ss0[j]);
            out[4 + j] = (f16)(xm1[j] * cc1[j] + sgn * xo1[j] * ss1[j]);
        }
        *(f16x8*)&Kws[(size_t)tile * 8192 + key * DH + dsw0] = out;
    } else {
        // ---- V path ----
        const int oc = gid - half;
        const int tile = oc >> 10, idx = oc & 1023;
        const int d = idx >> 3, c8 = idx & 7;          // d [0,128), 8 chunks/d-row
        const int ksw0 = c8 << 3;
        const int key0 = ksw0 ^ ((d & 7) << 3);        // 8-aligned, [0,64)
        const int kt = tile & 31, h = (tile >> 5) & 15, n = (tile >> 9) & 1, b = tile >> 10;
        const int t0 = n * CHUNKL + kt * KTILE + key0;
        const float* vp = V + ((size_t)(b * T_TOT + t0) * HH + h) * DH + d;
        f16x8 out;
#pragma unroll
        for (int j = 0; j < 8; ++j)
            out[j] = (f16)vp[(size_t)j * (HH * DH)];
        *(f16x8*)&VTws[(size_t)tile * 8192 + d * KTILE + ksw0] = out;
    }
}

// ---------------------------------------------------------------------------
// Fast attention: 256 threads = 4 waves, each wave 16 q-rows (block = 64 q-rows).
// Single-buffered K/V + per-wave P: 40KB LDS -> 4 blocks/CU. 16x16 MFMA swapped.
__global__ __launch_bounds__(256, 4)
void attn_fast_kernel(const float* __restrict__ Q, const f16* __restrict__ Kws,
                      const f16* __restrict__ VTws, const float* __restrict__ tab,
                      float* __restrict__ O)
{
    __shared__ f16 Kl[KTILE * DH];        // swizzled [key][d]   16 KB
    __shared__ f16 VTl[KTILE * DH];       // swizzled [d][key]   16 KB
    __shared__ f16 Pl[4][16 * 64];        // per-wave P [q][key], swizzled  8 KB

    // XCD-chunked: longest q-tiles first within each XCD chunk.
    const int bid = blockIdx.x;           // [0, 2048)
    const int sb  = (bid & 7) * 256 + (bid >> 3);
    const int qt  = 31 - (sb & 31);       // q-tile (64 rows), longest first
    const int bnh = sb >> 5;
    const int hd = bnh & 15, n = (bnh >> 4) & 1, b = bnh >> 5;

    const int tid = threadIdx.x;
    const int w   = tid >> 6;             // 0..3
    const int l   = tid & 63;
    const int g   = l >> 4;               // 0..3
    const int m   = l & 15;               // q column / key row / d row

    const int q0 = qt * 64;
    const size_t bh = (size_t)b * T_TOT * (HH * DH) + (size_t)hd * DH;
    const size_t tile0 = (size_t)bnh * (32 * 8192);

    // ---------------- Q fragments: RoPE'd via table, x log2(e) ------------------
    const int qr = q0 + w * 16 + m;       // chunk-local q row of this lane
    const int tg = n * CHUNKL + qr;
    const float* qp = Q + bh + (size_t)tg * (HH * DH);

    f16x8 qf[4];                          // [kc]: Q[q][d = kc*32 + 8g + j]
#pragma unroll
    for (int kc = 0; kc < 4; ++kc) {
        const int dbase = kc * 32 + g * 8;
        const int dl    = dbase & 63;
        f32x4 xa0 = *(const f32x4*)(qp + dbase);
        f32x4 xa1 = *(const f32x4*)(qp + dbase + 4);
        f32x4 xb0 = *(const f32x4*)(qp + (dbase ^ 64));
        f32x4 xb1 = *(const f32x4*)(qp + (dbase ^ 64) + 4);
        float cc[8], ss[8];
        *(f32x4*)&cc[0] = *(const f32x4*)(tab + tg * 64 + dl);
        *(f32x4*)&cc[4] = *(const f32x4*)(tab + tg * 64 + dl + 4);
        *(f32x4*)&ss[0] = *(const f32x4*)(tab + T_TOT * 64 + tg * 64 + dl);
        *(f32x4*)&ss[4] = *(const f32x4*)(tab + T_TOT * 64 + tg * 64 + dl + 4);
        const float sgn = (dbase < 64) ? -1.f : 1.f;
        float xa[8] = {xa0[0],xa0[1],xa0[2],xa0[3],xa1[0],xa1[1],xa1[2],xa1[3]};
        float xb[8] = {xb0[0],xb0[1],xb0[2],xb0[3],xb1[0],xb1[1],xb1[2],xb1[3]};
        f16x8 f;
#pragma unroll
        for (int j = 0; j < 8; ++j)
            f[j] = (f16)((xa[j] * cc[j] + sgn * xb[j] * ss[j]) * L2E);
        qf[kc] = f;
    }

    // accumulators: o[dt] = O[d = dt*16 + 4g + r][q = m-row]
    f32x4 o[8];
    float mrun = -NEGV, lrun = 0.f;       // per-lane, q = m; g-lanes duplicate
    const f32x4 ZERO4 = {0.f, 0.f, 0.f, 0.f};
#pragma unroll
    for (int dt = 0; dt < 8; ++dt) o[dt] = ZERO4;

    // ---------------- main loop: single-buffer, 2 barriers/tile -----------------
    const int nkt = qt + 1;

    for (int kt = 0; kt < nkt; ++kt) {
        // stage tile kt (32KB block-wide; 8 x 16B per thread)
        {
            const f16* ks_ = Kws  + tile0 + (size_t)kt * 8192;
            const f16* vs_ = VTws + tile0 + (size_t)kt * 8192;
#pragma unroll
            for (int i = 0; i < 4; ++i) {
                __builtin_amdgcn_global_load_lds(AS_G(ks_ + i * 2048 + tid * 8),
                                                 AS_L(&Kl[i * 2048 + tid * 8]), 16, 0, 0);
                __builtin_amdgcn_global_load_lds(AS_G(vs_ + i * 2048 + tid * 8),
                                                 AS_L(&VTl[i * 2048 + tid * 8]), 16, 0, 0);
            }
        }
        __syncthreads();                  // drains vmcnt: buf ready for all waves

        const bool active = (kt * KTILE) < (q0 + w * 16 + 16);
        if (active) {
            // ---- QK^T swapped: s[ts] = S[key = kt*64 + ts*16 + 4g + r][q = m] ----
            f32x4 s[4];
#pragma unroll
            for (int ts = 0; ts < 4; ++ts) s[ts] = ZERO4;

            __builtin_amdgcn_s_setprio(1);
#pragma unroll
            for (int kc = 0; kc < 4; ++kc) {
#pragma unroll
                for (int ts = 0; ts < 4; ++ts) {
                    const int key = ts * 16 + m;
                    f16x8 kf = *(const f16x8*)&Kl[key * DH + ((kc * 32 + 8 * g) ^ (m * 8))];
                    s[ts] = mfma16(kf, qf[kc], s[ts]);
                }
            }
            __builtin_amdgcn_s_setprio(0);

            // ---- mask (wave's diagonal tiles) ----
            if ((kt + 1) * KTILE > q0 + w * 16) {
#pragma unroll
                for (int ts = 0; ts < 4; ++ts)
#pragma unroll
                    for (int r = 0; r < 4; ++r) {
                        const int key = kt * KTILE + ts * 16 + 4 * g + r;
                        if (key > qr) s[ts][r] = -NEGV;
                    }
            }

            // ---- row max: in-lane tree (16 vals) + 2 shuffles ----
            float ma = fmaxf(fmaxf(s[0][0], s[0][1]), fmaxf(s[0][2], s[0][3]));
            float mb = fmaxf(fmaxf(s[1][0], s[1][1]), fmaxf(s[1][2], s[1][3]));
            float mc = fmaxf(fmaxf(s[2][0], s[2][1]), fmaxf(s[2][2], s[2][3]));
            float md = fmaxf(fmaxf(s[3][0], s[3][1]), fmaxf(s[3][2], s[3][3]));
            float mx = fmaxf(fmaxf(ma, mb), fmaxf(mc, md));
            mx = fmaxf(mx, __shfl_xor(mx, 16));
            mx = fmaxf(mx, __shfl_xor(mx, 32));

            // ---- defer-max rescale (q = m -> al lane-local) ----
            if (__any(mx > mrun + THRL2)) {
                const float mn = fmaxf(mrun, mx);
                const float al = exp2f(mrun - mn);
                mrun = mn;
                lrun *= al;
#pragma unroll
                for (int dt = 0; dt < 8; ++dt)
#pragma unroll
                    for (int r = 0; r < 4; ++r) o[dt][r] *= al;
            }

            // ---- p = exp2(s - m); lane-local partial sum ----
#pragma unroll
            for (int ts = 0; ts < 4; ++ts)
#pragma unroll
                for (int r = 0; r < 4; ++r) s[ts][r] = exp2f(s[ts][r] - mrun);
            {
                float p0 = (s[0][0] + s[0][1]) + (s[0][2] + s[0][3]);
                float p1 = (s[1][0] + s[1][1]) + (s[1][2] + s[1][3]);
                float p2 = (s[2][0] + s[2][1]) + (s[2][2] + s[2][3]);
                float p3 = (s[3][0] + s[3][1]) + (s[3][2] + s[3][3]);
                lrun += (p0 + p1) + (p2 + p3);
            }

            // ---- P -> per-wave LDS, 16B-block XOR swizzle (8B stores) ----
#pragma unroll
            for (int ts = 0; ts < 4; ++ts) {
                f16x4 pk;
                pk[0] = (f16)s[ts][0];
                pk[1] = (f16)s[ts][1];
                pk[2] = (f16)s[ts][2];
                pk[3] = (f16)s[ts][3];
                const int blk = (2 * ts + (g >> 1)) ^ (m & 7);
                *(f16x4*)&Pl[w][m * 64 + blk * 8 + (g & 1) * 4] = pk;
            }

            // ---- PV swapped: o[dt] += V^T(A) x P(B) ----
            __builtin_amdgcn_s_setprio(1);
#pragma unroll
            for (int kc = 0; kc < 2; ++kc) {
                f16x8 pb = *(const f16x8*)&Pl[w][m * 64 + ((kc * 4 + g) ^ (m & 7)) * 8];
#pragma unroll
                for (int dt = 0; dt < 8; ++dt) {
                    const int d = dt * 16 + m;
                    f16x8 vf = *(const f16x8*)&VTl[d * KTILE + ((kc * 32 + 8 * g) ^ ((m & 7) * 8))];
                    o[dt] = mfma16(vf, pb, o[dt]);
                }
            }
            __builtin_amdgcn_s_setprio(0);
        }

        __syncthreads();                  // all waves done reading buf -> safe to restage
    }

    // ---------------- epilogue: merge l across g, normalize, store --------------
    float lt = lrun;
    lt += __shfl_xor(lt, 16);
    lt += __shfl_xor(lt, 32);
    const float inv = 1.0f / lt;
    float* op = O + bh + (size_t)tg * (HH * DH);
#pragma unroll
    for (int dt = 0; dt < 8; ++dt) {
        f32x4 val;
#pragma unroll
        for (int r = 0; r < 4; ++r) val[r] = o[dt][r] * inv;
        *(f32x4*)&op[dt * 16 + 4 * g] = val;     // d = dt*16 + 4g + r
    }
}

// ---------------------------------------------------------------------------
// Fallback (no/small ws): self-contained, RoPE inline. (R2-style, known good.)
__global__ __launch_bounds__(256, 2)
void attn_kernel(const float* __restrict__ Q, const float* __restrict__ K,
                 const float* __restrict__ V, const int* __restrict__ startp,
                 float* __restrict__ O)
{
    __shared__ f16 Kl[KTILE * DH];
    __shared__ f16 VTl[DH * KTILE];
    __shared__ f16 Pl[4][32 * 72];

    const int bid = blockIdx.x;
    const int qt  = 15 - (bid & 15);
    const int bnh = bid >> 4;
    const int h = bnh & 15, n = (bnh >> 4) & 1, b = bnh >> 5;

    const int tid  = threadIdx.x;
    const int w    = tid >> 6;
    const int lane = tid & 63;
    const int g    = lane >> 4, m = lane & 15;

    const int q0 = qt * 128;
    const size_t bh = (size_t)b * T_TOT * (HH * DH) + (size_t)h * DH;
    const int start = *startp;

    f16x8  qf[2][4];
    float  mrun[2][4], lrun[2][4];
    f32x4  o[2][8];
    const f32x4 ZERO4 = {0.f, 0.f, 0.f, 0.f};

#pragma unroll
    for (int rs = 0; rs < 2; ++rs) {
#pragma unroll
        for (int r = 0; r < 4; ++r) { mrun[rs][r] = -NEGV; lrun[rs][r] = 0.f; }
#pragma unroll
        for (int dt = 0; dt < 8; ++dt) o[rs][dt] = ZERO4;

        const int tg = n * CHUNKL + q0 + w * 32 + rs * 16 + m;
        const float* qp = Q + bh + (size_t)tg * (HH * DH);
#pragma unroll
        for (int kc = 0; kc < 4; ++kc) {
            const int dbase = kc * 32 + g * 8;
            const int dlo   = dbase & 63;
            f32x4 xa0 = *(const f32x4*)(qp + dbase);
            f32x4 xa1 = *(const f32x4*)(qp + dbase + 4);
            f32x4 xb0 = *(const f32x4*)(qp + (dbase ^ 64));
            f32x4 xb1 = *(const f32x4*)(qp + (dbase ^ 64) + 4);
            float cc[8], ss[8];
#pragma unroll
            for (int j = 0; j < 8; ++j) {
                float invf = expf((float)(dlo + j) * (-9.210340371976184f / 64.0f));
                sincosf((float)(tg + start) * invf, &ss[j], &cc[j]);
            }
            const float sgn = (dbase < 64) ? -1.f : 1.f;
            float xa[8] = {xa0[0],xa0[1],xa0[2],xa0[3],xa1[0],xa1[1],xa1[2],xa1[3]};
            float xb[8] = {xb0[0],xb0[1],xb0[2],xb0[3],xb1[0],xb1[1],xb1[2],xb1[3]};
            f16x8 f;
#pragma unroll
            for (int j = 0; j < 8; ++j) f[j] = (f16)(xa[j] * cc[j] + sgn * xb[j] * ss[j]);
            qf[rs][kc] = f;
        }
    }

    const int nkt = 2 * qt + 2;
    for (int kt = 0; kt < nkt; ++kt) {
        __syncthreads();
#pragma unroll
        for (int it = 0; it < 4; ++it) {
            const int tau = tid + 256 * it;
            const int row = tau >> 4;
            const int d0  = (tau & 15) << 2;
            const int tg  = n * CHUNKL + kt * KTILE + row;
            const float* kp = K + bh + (size_t)tg * (HH * DH);
            f32x4 xa = *(const f32x4*)(kp + d0);
            f32x4 xb = *(const f32x4*)(kp + d0 + 64);
            f32x4 cc, ss;
#pragma unroll
            for (int j = 0; j < 4; ++j) {
                float invf = expf((float)(d0 + j) * (-9.210340371976184f / 64.0f));
                float sv, cv;
                sincosf((float)(tg + start) * invf, &sv, &cv);
                cc[j] = cv; ss[j] = sv;
            }
            f16x4 oA, oB;
#pragma unroll
            for (int j = 0; j < 4; ++j) {
                oA[j] = (f16)(xa[j] * cc[j] - xb[j] * ss[j]);
                oB[j] = (f16)(xb[j] * cc[j] + xa[j] * ss[j]);
            }
            const int sw = (row & 7) << 3;
            *(f16x4*)&Kl[row * DH + (d0 ^ sw)]        = oA;
            *(f16x4*)&Kl[row * DH + ((d0 + 64) ^ sw)] = oB;
        }
#pragma unroll
        for (int it = 0; it < 8; ++it) {
            const int tau = tid + 256 * it;
            const int key = tau & 63;
            const int d0  = (tau >> 6) << 2;
            const int tg  = n * CHUNKL + kt * KTILE + key;
            f32x4 x = *(const f32x4*)(V + bh + (size_t)tg * (HH * DH) + d0);
#pragma unroll
            for (int j = 0; j < 4; ++j) {
                const int d = d0 + j;
                VTl[d * KTILE + (key ^ ((d & 7) << 3))] = (f16)x[j];
            }
        }
        __syncthreads();

        const bool active = (kt * KTILE) < (q0 + w * 32 + 32);
        if (active) {
            f32x4 sa[2][4];
#pragma unroll
            for (int rs = 0; rs < 2; ++rs)
#pragma unroll
                for (int nt = 0; nt < 4; ++nt) sa[rs][nt] = ZERO4;
#pragma unroll
            for (int nt = 0; nt < 4; ++nt) {
                const int key = nt * 16 + m;
                const int swk = (key & 7) << 3;
#pragma unroll
                for (int kc = 0; kc < 4; ++kc) {
                    f16x8 bf = *(const f16x8*)&Kl[key * DH + ((kc * 32 + g * 8) ^ swk)];
                    sa[0][nt] = mfma16(qf[0][kc], bf, sa[0][nt]);
                    sa[1][nt] = mfma16(qf[1][kc], bf, sa[1][nt]);
                }
            }
            const bool domask = (kt >= 2 * qt);
#pragma unroll
            for (int rs = 0; rs < 2; ++rs) {
                if (domask) {
#pragma unroll
                    for (int nt = 0; nt < 4; ++nt) {
                        const int key = kt * KTILE + nt * 16 + m;
#pragma unroll
                        for (int r = 0; r < 4; ++r) {
                            const int qr = q0 + w * 32 + rs * 16 + 4 * g + r;
                            if (key > qr) sa[rs][nt][r] = -NEGV;
                        }
                    }
                }
                float mx[4];
#pragma unroll
                for (int r = 0; r < 4; ++r)
                    mx[r] = fmaxf(fmaxf(sa[rs][0][r], sa[rs][1][r]),
                                  fmaxf(sa[rs][2][r], sa[rs][3][r]));
#pragma unroll
                for (int off = 1; off < 16; off <<= 1)
#pragma unroll
                    for (int r = 0; r < 4; ++r)
                        mx[r] = fmaxf(mx[r], __shfl_xor(mx[r], off));
                float al[4], ps[4];
#pragma unroll
                for (int r = 0; r < 4; ++r) {
                    const float mn = fmaxf(mrun[rs][r], mx[r]);
                    al[r] = exp2f((mrun[rs][r] - mn) * L2E);
                    mrun[rs][r] = mn;
                    ps[r] = 0.f;
                }
#pragma unroll
                for (int nt = 0; nt < 4; ++nt)
#pragma unroll
                    for (int r = 0; r < 4; ++r) {
                        const float p = exp2f((sa[rs][nt][r] - mrun[rs][r]) * L2E);
                        sa[rs][nt][r] = p;
                        ps[r] += p;
                    }
#pragma unroll
                for (int off = 1; off < 16; off <<= 1)
#pragma unroll
                    for (int r = 0; r < 4; ++r)
                        ps[r] += __shfl_xor(ps[r], off);
#pragma unroll
                for (int r = 0; r < 4; ++r)
                    lrun[rs][r] = lrun[rs][r] * al[r] + ps[r];
#pragma unroll
                for (int dt = 0; dt < 8; ++dt)
#pragma unroll
                    for (int r = 0; r < 4; ++r)
                        o[rs][dt][r] *= al[r];
#pragma unroll
                for (int nt = 0; nt < 4; ++nt)
#pragma unroll
                    for (int r = 0; r < 4; ++r)
                        Pl[w][(rs * 16 + 4 * g + r) * 72 + nt * 16 + m] = (f16)sa[rs][nt][r];
            }
            f16x8 pa[2][2];
#pragma unroll
            for (int rs = 0; rs < 2; ++rs)
#pragma unroll
                for (int kc = 0; kc < 2; ++kc)
                    pa[rs][kc] = *(const f16x8*)&Pl[w][(rs * 16 + m) * 72 + kc * 32 + g * 8];
#pragma unroll
            for (int dt = 0; dt < 8; ++dt) {
                const int d   = dt * 16 + m;
                const int swv = (d & 7) << 3;
#pragma unroll
                for (int kc = 0; kc < 2; ++kc) {
                    f16x8 vf = *(const f16x8*)&VTl[d * KTILE + ((kc * 32 + g * 8) ^ swv)];
                    o[0][dt] = mfma16(pa[0][kc], vf, o[0][dt]);
                    o[1][dt] = mfma16(pa[1][kc], vf, o[1][dt]);
                }
            }
        }
    }

#pragma unroll
    for (int rs = 0; rs < 2; ++rs) {
#pragma unroll
        for (int r = 0; r < 4; ++r) {
            const float inv = 1.0f / lrun[rs][r];
            const int tg = n * CHUNKL + q0 + w * 32 + rs * 16 + 4 * g + r;
            float* op = O + bh + (size_t)tg * (HH * DH);
#pragma unroll
            for (int dt = 0; dt < 8; ++dt)
                op[dt * 16 + m] = o[rs][dt][r] * inv;
        }
    }
}

extern "C" void kernel_launch(void* const* d_in, const int* in_sizes, int n_in,
                              void* d_out, int out_size, void* d_ws, size_t ws_size,
                              hipStream_t stream) {
    const float* q = (const float*)d_in[0];
    const float* k = (const float*)d_in[1];
    const float* v = (const float*)d_in[2];
    const int* start = (const int*)d_in[3];
    float* out = (float*)d_out;

    const size_t tab_elems = (size_t)2 * T_TOT * 64;               // 2MB
    const size_t kv_elems  = (size_t)2 * T_TOT * HH * DH;          // 32MB each (f16)
    const size_t need = tab_elems * sizeof(float) + 2 * kv_elems * sizeof(f16); // 66MB

    if (ws_size >= need) {
        float* tab = (float*)d_ws;
        f16* Kws  = (f16*)((char*)d_ws + tab_elems * sizeof(float));
        f16* VTws = Kws + kv_elems;
        rope_table_kernel<<<(T_TOT * 64) / 256, 256, 0, stream>>>(tab, start);
        prep_kv_kernel<<<(int)(2 * (kv_elems / 8) / 256), 256, 0, stream>>>(k, v, tab, Kws, VTws);
        attn_fast_kernel<<<2048, 256, 0, stream>>>(q, Kws, VTws, tab, out);
    } else {
        attn_kernel<<<64 * 16, 256, 0, stream>>>(q, k, v, start, out);
    }
}